// Round 10
// baseline (170.871 us; speedup 1.0000x reference)
//
#include <hip/hip_runtime.h>
#include <hip/hip_bf16.h>

typedef __attribute__((ext_vector_type(8))) short short8;
typedef __attribute__((ext_vector_type(4))) float float4v;
typedef __attribute__((ext_vector_type(4))) short short4v;
typedef __attribute__((ext_vector_type(4))) unsigned int uint4v;
typedef __attribute__((ext_vector_type(2))) unsigned int uint2v;

#define B_ 2
#define S_ 2048
#define D_ 1024
#define H_ 16
#define HD_ 64
#define M_ 4096
#define LOG2E 1.442695040888963f

__device__ __forceinline__ unsigned short f2bf(float f) {
  unsigned int u = __builtin_bit_cast(unsigned int, f);
  u += 0x7fffu + ((u >> 16) & 1u);   // RNE (finite values only)
  return (unsigned short)(u >> 16);
}

// packed f32x2 -> bf16x2 (RNE), one v_cvt_pk_bf16_f32
__device__ __forceinline__ unsigned int pkbf(float a, float b) {
  __hip_bfloat162 h = __float22bfloat162_rn(make_float2(a, b));
  unsigned int u;
  __builtin_memcpy(&u, &h, sizeof(u));
  return u;
}

__device__ __forceinline__ float max3f(float a, float b, float c) {
  return fmaxf(fmaxf(a, b), c);   // clang fuses to v_max3_f32
}

__device__ __forceinline__ void gload_lds16(const void* g, void* l) {
  __builtin_amdgcn_global_load_lds(
      (const __attribute__((address_space(1))) void*)g,
      (__attribute__((address_space(3))) void*)l, 16, 0, 0);
}

// ---------------------------------------------------------------------------
// f32 -> bf16 cast (unchanged).
// ---------------------------------------------------------------------------
__global__ __launch_bounds__(256, 4) void cvt_kernel(
    const float* __restrict__ x,  const float* __restrict__ qw,
    const float* __restrict__ kw, const float* __restrict__ vw,
    const float* __restrict__ ow, unsigned short* __restrict__ dst)
{
  const int seg = blockIdx.y;
  const float* src;
  size_t doff;
  if (seg < 4)       { src = x + (size_t)seg * 1048576; doff = (size_t)seg * 1048576; }
  else if (seg == 4) { src = qw; doff = 4194304u; }
  else if (seg == 5) { src = kw; doff = 4194304u + 1048576u; }
  else if (seg == 6) { src = vw; doff = 4194304u + 2097152u; }
  else               { src = ow; doff = 4194304u + 3145728u; }
  const size_t i = ((size_t)blockIdx.x * 256 + threadIdx.x) * 4;
  float4v v = *(const float4v*)(src + i);
  short4v p;
#pragma unroll
  for (int r = 0; r < 4; ++r) p[r] = (short)f2bf(v[r]);
  *(short4v*)(dst + doff + i) = p;
}

// ---------------------------------------------------------------------------
// GEMM: out = X @ W^T + bias.  Round 10: attn-style single-barrier prefetch
// K-loop.  BK=32, double-buffered staging (LDS unchanged: 32KB TN=128 /
// 24KB TN=64, 3 blocks/CU): one __syncthreads per K-step; loads for k+32
// issued right after the barrier, consumed next iteration -> the vmcnt(0)
// drain at the barrier sees loads that already had a full compute phase to
// land (removes the 2-barrier shape's exposed-latency stall).  BK=32 rows
// are 64B (4 chunks) -> pair-swizzle chunk^((row>>1)&3), applied on the
// pre-swizzled global source and the read side (rule 21); 2 lanes/bank = free.
// ---------------------------------------------------------------------------
template <int TN>
__global__ __launch_bounds__(256, 3) void gemm_kernel(
    const unsigned short* __restrict__ X,
    const unsigned short* __restrict__ W0, const unsigned short* __restrict__ W1,
    const unsigned short* __restrict__ W2,
    const float* __restrict__ Bi0, const float* __restrict__ Bi1,
    const float* __restrict__ Bi2,
    unsigned short* O0, unsigned short* O1, unsigned short* O2,
    float* OutF, int md0, int md1, int md2)
{
  constexpr int NJ = TN / 32;     // 16-col acc tiles per wave
  constexpr int BSZ = (TN == 128) ? 8192 : 4096;        // one Bs buffer
  constexpr int SMEM = 16384 + 2 * BSZ;                 // As dbuf + Bs dbuf
  constexpr int GX = (TN == 128) ? 8 : 16;   // gridDim.x (compile-time)
  constexpr int CPX = (GX * 32) / 8;         // blocks per XCD chunk
  const int z = blockIdx.z;
  const unsigned short* W  = (z == 0) ? W0  : ((z == 1) ? W1  : W2);
  const float* Bi          = (z == 0) ? Bi0 : ((z == 1) ? Bi1 : Bi2);
  unsigned short* Out      = (z == 0) ? O0  : ((z == 1) ? O1  : O2);
  const int mode           = (z == 0) ? md0 : ((z == 1) ? md1 : md2);

  __shared__ __align__(16) char smem[SMEM];
  char* AsB = smem;              // 2 x 8KB
  char* BsB = smem + 16384;      // 2 x BSZ
  float* tb = (float*)smem;      // mode-1 transpose buffer (aliases staging)

  const int t = threadIdx.x, l = t & 63;
  const int w = t >> 6, lr = l & 15, lg = l >> 4;

  // XCD swizzle: dispatch slot bid -> logical tile sw (bijective, nwg%8==0)
  const int bid = (int)blockIdx.y * GX + (int)blockIdx.x;
  const int sw  = (bid & 7) * CPX + (bid >> 3);
  const int n0 = (sw % GX) * TN, m0 = (sw / GX) * 128;
  const int wm = (w >> 1) * 64, wn = (w & 1) * (TN / 2);

  float4v acc[4][NJ];
#pragma unroll
  for (int i = 0; i < 4; ++i)
#pragma unroll
    for (int j = 0; j < NJ; ++j) acc[i][j] = (float4v){0.f, 0.f, 0.f, 0.f};

  // staging decomposition (per 8KB tile = 512 chunks of 16B):
  // idx -> row = idx>>2, chunk = idx&3; source pre-swizzled by pair-swizzle
  const int ia0 = t, ia1 = t + 256;
  const int ar0 = ia0 >> 2, ac0 = (ia0 & 3) ^ ((ar0 >> 1) & 3);
  const int ar1 = ia1 >> 2, ac1 = (ia1 & 3) ^ ((ar1 >> 1) & 3);

  auto stage = [&](char* Ab, char* Bb, int k0) {
    gload_lds16(X + (size_t)(m0 + ar0) * 1024 + k0 + ac0 * 8, Ab + ia0 * 16);
    gload_lds16(X + (size_t)(m0 + ar1) * 1024 + k0 + ac1 * 8, Ab + ia1 * 16);
    gload_lds16(W + (size_t)(n0 + ar0) * 1024 + k0 + ac0 * 8, Bb + ia0 * 16);
    if (TN == 128)
      gload_lds16(W + (size_t)(n0 + ar1) * 1024 + k0 + ac1 * 8, Bb + ia1 * 16);
  };

  stage(AsB, BsB, 0);   // prologue: tile 0 into buffer 0

  for (int k0 = 0; k0 < 1024; k0 += 32) {
    const int b = (k0 >> 5) & 1;
    char* Ab = AsB + b * 8192;
    char* Bb = BsB + b * BSZ;
    __syncthreads();    // buffer b ready (drains loads issued last iter)
    if (k0 + 32 < 1024)
      stage(AsB + (b ^ 1) * 8192, BsB + (b ^ 1) * BSZ, k0 + 32);

    short8 af[4], bfr[NJ];
#pragma unroll
    for (int i = 0; i < 4; ++i) {
      const int row = wm + i * 16 + lr;
      af[i] = *(const short8*)(Ab + row * 64 + ((lg ^ ((row >> 1) & 3)) << 4));
    }
#pragma unroll
    for (int j = 0; j < NJ; ++j) {
      const int row = wn + j * 16 + lr;
      bfr[j] = *(const short8*)(Bb + row * 64 + ((lg ^ ((row >> 1) & 3)) << 4));
    }
#pragma unroll
    for (int i = 0; i < 4; ++i)
#pragma unroll
      for (int j = 0; j < NJ; ++j)
        acc[i][j] = __builtin_amdgcn_mfma_f32_16x16x32_bf16(af[i], bfr[j], acc[i][j], 0, 0, 0);
  }

  float bv[NJ];
#pragma unroll
  for (int j = 0; j < NJ; ++j) bv[j] = Bi[n0 + wn + j * 16 + lr];

  if constexpr (TN == 128) {
    if (mode == 1) {
      __syncthreads();   // staging LDS now dead; safe to overwrite as tb
      const int rbase = (w >> 1) * 16;
      const int row16 = t >> 3, chunk = t & 7;
#pragma unroll
      for (int i = 0; i < 4; ++i) {
#pragma unroll
        for (int j = 0; j < 4; ++j)
#pragma unroll
          for (int r = 0; r < 4; ++r)
            tb[(rbase + lg * 4 + r) * 132 + wn + j * 16 + lr] = acc[i][j][r] + bv[j];
        __syncthreads();
        const int grow = m0 + ((row16 < 16) ? (i * 16 + row16) : (64 + i * 16 + row16 - 16));
        const int b = grow >> 11, sl = grow & 2047;
        const int colg = n0 + chunk * 16;
        const int hh = colg >> 6, d0 = colg & 63;
        float4v v4[4];
#pragma unroll
        for (int q = 0; q < 4; ++q)
          v4[q] = *(const float4v*)(tb + row16 * 132 + chunk * 16 + q * 4);
        uint4v lo, hi;
#pragma unroll
        for (int q = 0; q < 2; ++q) {
          lo[q * 2]     = pkbf(v4[q][0], v4[q][1]);
          lo[q * 2 + 1] = pkbf(v4[q][2], v4[q][3]);
          hi[q * 2]     = pkbf(v4[q + 2][0], v4[q + 2][1]);
          hi[q * 2 + 1] = pkbf(v4[q + 2][2], v4[q + 2][3]);
        }
        unsigned short* dst = Out + ((size_t)(b * H_ + hh) * S_ + sl) * HD_ + d0;
        *(short8*)dst = __builtin_bit_cast(short8, lo);
        *(short8*)(dst + 8) = __builtin_bit_cast(short8, hi);
        __syncthreads();
      }
      return;
    }
    if (mode == 2) {
#pragma unroll
      for (int i = 0; i < 4; ++i) {
        const int rowb = m0 + wm + i * 16 + lg * 4;
#pragma unroll
        for (int j = 0; j < 4; ++j) {
          const int col = n0 + wn + j * 16 + lr;
          const int b = rowb >> 11, s = rowb & 2047;
          const int hh = col >> 6, d = col & 63;
          // k-group interleave within each 32-elem s-block (see header)
          const int gI = (s >> 2) & 7;
          const int gP = ((gI & 3) << 1) | (gI >> 2);
          const int sN = (s & ~31) | (gP << 2);
          uint2v pk2;
          pk2[0] = pkbf(acc[i][j][0] + bv[j], acc[i][j][1] + bv[j]);
          pk2[1] = pkbf(acc[i][j][2] + bv[j], acc[i][j][3] + bv[j]);
          *(short4v*)(Out + ((size_t)(b * H_ + hh) * HD_ + d) * S_ + sN) =
              __builtin_bit_cast(short4v, pk2);
        }
      }
      return;
    }
  }
  // mode 0: f32 out
#pragma unroll
  for (int i = 0; i < 4; ++i) {
    const int rowb = m0 + wm + i * 16 + lg * 4;
#pragma unroll
    for (int j = 0; j < NJ; ++j) {
      const int col = n0 + wn + j * 16 + lr;
#pragma unroll
      for (int r = 0; r < 4; ++r)
        OutF[(size_t)(rowb + r) * 1024 + col] = acc[i][j][r] + bv[j];
    }
  }
}

// ---------------------------------------------------------------------------
// Flash attention v12 (unchanged -- round-9 winner): v9 structure with
// REVERSED tile order (j from the diagonal down to 0).  ALiBi max-score
// decreases per tile, so the defer-max rescale stops firing after tile 1.
// ---------------------------------------------------------------------------
__global__ __launch_bounds__(256, 4) void attn_kernel(
    const unsigned short* __restrict__ Q, const unsigned short* __restrict__ K,
    const unsigned short* __restrict__ VT, unsigned short* __restrict__ O)
{
  // K dbuf 2x8KB + V dbuf 2x8KB; epilogue transpose buffer aliases [0,17664)
  __shared__ __align__(16) char smem[32768];

  const int t = threadIdx.x, l = t & 63;
  const int w = t >> 6, lr = l & 15, lg = l >> 4;
  const int bh = blockIdx.x;
  const int it = 31 - (int)blockIdx.y;   // LPT: heavy tiles first
  const int h = bh & 15;

  const unsigned short* qbp = Q + (size_t)bh * S_ * HD_;
  const unsigned short* kbp = K + (size_t)bh * S_ * HD_;
  const unsigned short* vbp = VT + (size_t)bh * HD_ * S_;

  const float slope2 = __builtin_amdgcn_exp2f(-0.5f * (float)(h + 1)) * LOG2E;
  const float qksc = 0.125f * LOG2E;

  const int g0 = t, g1 = t + 256;
  const int sr0 = g0 >> 3, sc0 = (g0 & 7) ^ (sr0 & 7);
  const int sr1 = g1 >> 3, sc1 = (g1 & 7) ^ (sr1 & 7);

  const int fchunk = ((4 + lg) ^ (lr & 7)) * 16;   // ks=1
  const int fchunk0 = ((lg) ^ (lr & 7)) * 16;      // ks=0

  const int qrow = it * 64 + w * 16;
  const int qpos = qrow + lr;

  short8 ones;
#pragma unroll
  for (int e = 0; e < 8; ++e) ones[e] = (short)0x3F80;  // bf16 1.0

  short8 qf[2];
#pragma unroll
  for (int ks = 0; ks < 2; ++ks)
    qf[ks] = *(const short8*)(qbp + (size_t)(qrow + lr) * HD_ + ks * 32 + lg * 8);

  // hoisted ALiBi bias constants: kb[nj*4+r] = slope2*(nj*16+lg*4+r)
  float kb[16];
#pragma unroll
  for (int nj = 0; nj < 4; ++nj)
#pragma unroll
    for (int r = 0; r < 4; ++r)
      kb[nj * 4 + r] = slope2 * (float)(nj * 16 + lg * 4 + r);
  const float jbstep = slope2 * 64.0f;
  float jb = jbstep * (float)it;            // slope2 * 64 * j, descending

  const float4v z4 = (float4v){0.f, 0.f, 0.f, 0.f};

  float4v o_acc[4], l_acc;
#pragma unroll
  for (int dt = 0; dt < 4; ++dt) o_acc[dt] = z4;
  l_acc = z4;
  float m_st = -1e30f;

  // prefetch tile j=it into buffer (it&1)
  {
    char* K0 = smem + ((it & 1) ? 8192 : 0);
    char* V0 = smem + 16384 + ((it & 1) ? 8192 : 0);
    gload_lds16(kbp + (size_t)(it * 64 + sr0) * HD_ + sc0 * 8, K0 + g0 * 16);
    gload_lds16(kbp + (size_t)(it * 64 + sr1) * HD_ + sc1 * 8, K0 + g1 * 16);
    gload_lds16(vbp + (size_t)sr0 * S_ + it * 64 + sc0 * 8, V0 + g0 * 16);
    gload_lds16(vbp + (size_t)sr1 * S_ + it * 64 + sc1 * 8, V0 + g1 * 16);
  }
  __syncthreads();

  const int vcl = lr & 7;

  for (int j = it; j >= 0; --j) {
    const int cur = j & 1;
    char* Ks = smem + (cur ? 8192 : 0);
    char* Vs = smem + 16384 + (cur ? 8192 : 0);
    if (j > 0) {
      char* Kn = smem + (cur ? 0 : 8192);
      char* Vn = smem + 16384 + (cur ? 0 : 8192);
      const int jn = j - 1;
      gload_lds16(kbp + (size_t)(jn * 64 + sr0) * HD_ + sc0 * 8, Kn + g0 * 16);
      gload_lds16(kbp + (size_t)(jn * 64 + sr1) * HD_ + sc1 * 8, Kn + g1 * 16);
      gload_lds16(vbp + (size_t)sr0 * S_ + jn * 64 + sc0 * 8, Vn + g0 * 16);
      gload_lds16(vbp + (size_t)sr1 * S_ + jn * 64 + sc1 * 8, Vn + g1 * 16);
    }

    // S^T = K Q^T
    float4v s_acc[4];
    __builtin_amdgcn_s_setprio(1);
#pragma unroll
    for (int nj = 0; nj < 4; ++nj) {
      short8 kf0 = *(const short8*)(Ks + (nj * 16 + lr) * 128 + fchunk0);
      float4v t0 = __builtin_amdgcn_mfma_f32_16x16x32_bf16(kf0, qf[0], z4, 0, 0, 0);
      short8 kf1 = *(const short8*)(Ks + (nj * 16 + lr) * 128 + fchunk);
      s_acc[nj] = __builtin_amdgcn_mfma_f32_16x16x32_bf16(kf1, qf[1], t0, 0, 0, 0);
    }
    __builtin_amdgcn_s_setprio(0);

    // scale + ALiBi (jb-relative domain: t = s*qksc + kb_e; absolute = t + jb)
#pragma unroll
    for (int nj = 0; nj < 4; ++nj)
#pragma unroll
      for (int r = 0; r < 4; ++r)
        s_acc[nj][r] = s_acc[nj][r] * qksc + kb[nj * 4 + r];
    if (j == it) {
#pragma unroll
      for (int nj = 0; nj < 4; ++nj)
#pragma unroll
        for (int r = 0; r < 4; ++r) {
          const int kpos = j * 64 + nj * 16 + lg * 4 + r;
          if (kpos > qpos) s_acc[nj][r] = -1e30f;
        }
    }

    // online softmax: max3 tree + 2 cross-quad shuffles; defer-max THR=8
    float a0 = max3f(s_acc[0][0], s_acc[0][1], s_acc[0][2]);
    float a1 = max3f(s_acc[0][3], s_acc[1][0], s_acc[1][1]);
    float a2 = max3f(s_acc[1][2], s_acc[1][3], s_acc[2][0]);
    float a3 = max3f(s_acc[2][1], s_acc[2][2], s_acc[2][3]);
    float a4 = max3f(s_acc[3][0], s_acc[3][1], s_acc[3][2]);
    float b0 = max3f(a0, a1, a2);
    float b1 = max3f(a3, a4, s_acc[3][3]);
    float mxt = fmaxf(b0, b1);
    mxt = fmaxf(mxt, __shfl_xor(mxt, 16, 64));
    mxt = fmaxf(mxt, __shfl_xor(mxt, 32, 64));
    const float mx = mxt + jb;               // absolute-domain tile max
    if (__any(mx > m_st + 8.0f)) {
      const float mn = fmaxf(m_st, mx);
      const float alpha = __builtin_amdgcn_exp2f(m_st - mn);
      m_st = mn;
#pragma unroll
      for (int dt = 0; dt < 4; ++dt)
#pragma unroll
        for (int r = 0; r < 4; ++r) o_acc[dt][r] *= alpha;
#pragma unroll
      for (int r = 0; r < 4; ++r) l_acc[r] *= alpha;
    }
    const float c1 = m_st - jb;              // exp2 arg = t - c1 = abs - m_st
#pragma unroll
    for (int nj = 0; nj < 4; ++nj)
#pragma unroll
      for (int r = 0; r < 4; ++r)
        s_acc[nj][r] = __builtin_amdgcn_exp2f(s_acc[nj][r] - c1);

    // P^T -> bf16 K=32 B-fragments via packed cvt
    short8 pT[2];
#pragma unroll
    for (int njp = 0; njp < 2; ++njp) {
      uint4v u;
      u[0] = pkbf(s_acc[njp * 2][0], s_acc[njp * 2][1]);
      u[1] = pkbf(s_acc[njp * 2][2], s_acc[njp * 2][3]);
      u[2] = pkbf(s_acc[njp * 2 + 1][0], s_acc[njp * 2 + 1][1]);
      u[3] = pkbf(s_acc[njp * 2 + 1][2], s_acc[njp * 2 + 1][3]);
      pT[njp] = __builtin_bit_cast(short8, u);
    }

    __builtin_amdgcn_s_setprio(1);
    // l += rowsum(P) via ones-A MFMA (off the critical path, runs with PV)
    l_acc = __builtin_amdgcn_mfma_f32_16x16x32_bf16(ones, pT[0], l_acc, 0, 0, 0);
    l_acc = __builtin_amdgcn_mfma_f32_16x16x32_bf16(ones, pT[1], l_acc, 0, 0, 0);

    // O^T += V^T P^T  (interleaved VT: one b128 per fragment, conflict-free)
#pragma unroll
    for (int dt = 0; dt < 4; ++dt) {
      const char* rowp = Vs + (dt * 16 + lr) * 128;
#pragma unroll
      for (int njp = 0; njp < 2; ++njp) {
        short8 vf8 = *(const short8*)(rowp + (((njp * 4 + lg) ^ vcl) << 4));
        o_acc[dt] = __builtin_amdgcn_mfma_f32_16x16x32_bf16(vf8, pT[njp], o_acc[dt], 0, 0, 0);
      }
    }
    __builtin_amdgcn_s_setprio(0);
    jb -= jbstep;
    __syncthreads();
  }

  // epilogue: un-transpose O^T via wave-private LDS (aliases dead K dbuf)
  char* tw = smem + w * 4416;
#pragma unroll
  for (int dt = 0; dt < 4; ++dt)
#pragma unroll
    for (int r = 0; r < 4; ++r)
      *(float*)(tw + ((dt * 16 + lg * 4 + r) * 17 + lr) * 4) = o_acc[dt][r];
  if (lg == 0) *(float*)(tw + 4352 + lr * 4) = l_acc[0];

  const int q2 = l >> 2, dbase = (l & 3) * 16;
  const float invl = 1.0f / *(const float*)(tw + 4352 + q2 * 4);
  uint4v os0, os1;
#pragma unroll
  for (int k = 0; k < 8; ++k) {
    const float va = *(const float*)(tw + ((dbase + 2 * k) * 17 + q2) * 4) * invl;
    const float vb = *(const float*)(tw + ((dbase + 2 * k + 1) * 17 + q2) * 4) * invl;
    if (k < 4) os0[k] = pkbf(va, vb); else os1[k - 4] = pkbf(va, vb);
  }
  const int brow = (bh >> 4) * S_;
  unsigned short* op = O + (size_t)(brow + qrow + q2) * 1024 + h * 64 + dbase;
  *(short8*)op = __builtin_bit_cast(short8, os0);
  *(short8*)(op + 8) = __builtin_bit_cast(short8, os1);
}

extern "C" void kernel_launch(void* const* d_in, const int* in_sizes, int n_in,
                              void* d_out, int out_size, void* d_ws, size_t ws_size,
                              hipStream_t stream) {
  (void)in_sizes; (void)n_in; (void)out_size; (void)ws_size;
  const float* x  = (const float*)d_in[0];
  const float* qw = (const float*)d_in[1];
  const float* qb = (const float*)d_in[2];
  const float* kw = (const float*)d_in[3];
  const float* kb = (const float*)d_in[4];
  const float* vw = (const float*)d_in[5];
  const float* vb = (const float*)d_in[6];
  const float* ow = (const float*)d_in[7];
  const float* ob = (const float*)d_in[8];
  float* out = (float*)d_out;

  unsigned short* xb  = (unsigned short*)d_ws;              // [4096,1024] bf16
  unsigned short* qwb = xb  + (size_t)M_ * D_;
  unsigned short* kwb = qwb + (size_t)D_ * D_;
  unsigned short* vwb = kwb + (size_t)D_ * D_;
  unsigned short* owb = vwb + (size_t)D_ * D_;
  unsigned short* qws = owb + (size_t)D_ * D_;              // [B,H,S,hd]
  unsigned short* kws = qws + (size_t)M_ * D_;              // [B,H,S,hd]
  unsigned short* vws = kws + (size_t)M_ * D_;              // [B,H,hd,S] interleaved
  unsigned short* aws = vws + (size_t)M_ * D_;              // [B*S, H*hd]

  cvt_kernel<<<dim3(1024, 8), dim3(256), 0, stream>>>(x, qw, kw, vw, ow, xb);
  gemm_kernel<128><<<dim3(8, 32, 3), dim3(256), 0, stream>>>(
      xb, qwb, kwb, vwb, qb, kb, vb, qws, kws, vws, out, 1, 1, 2);
  attn_kernel<<<dim3(32, 32), dim3(256), 0, stream>>>(qws, kws, vws, aws);
  gemm_kernel<64><<<dim3(16, 32, 1), dim3(256), 0, stream>>>(
      aws, owb, owb, owb, ob, ob, ob, aws, aws, aws, out, 0, 0, 0);
}

// Round 11
// 165.790 us; speedup vs baseline: 1.0306x; 1.0306x over previous
//
#include <hip/hip_runtime.h>
#include <hip/hip_bf16.h>

typedef __attribute__((ext_vector_type(8))) short short8;
typedef __attribute__((ext_vector_type(4))) float float4v;
typedef __attribute__((ext_vector_type(4))) short short4v;
typedef __attribute__((ext_vector_type(4))) unsigned int uint4v;
typedef __attribute__((ext_vector_type(2))) unsigned int uint2v;

#define B_ 2
#define S_ 2048
#define D_ 1024
#define H_ 16
#define HD_ 64
#define M_ 4096
#define LOG2E 1.442695040888963f

__device__ __forceinline__ unsigned short f2bf(float f) {
  unsigned int u = __builtin_bit_cast(unsigned int, f);
  u += 0x7fffu + ((u >> 16) & 1u);   // RNE (finite values only)
  return (unsigned short)(u >> 16);
}

// packed f32x2 -> bf16x2 (RNE), one v_cvt_pk_bf16_f32
__device__ __forceinline__ unsigned int pkbf(float a, float b) {
  __hip_bfloat162 h = __float22bfloat162_rn(make_float2(a, b));
  unsigned int u;
  __builtin_memcpy(&u, &h, sizeof(u));
  return u;
}

__device__ __forceinline__ float max3f(float a, float b, float c) {
  return fmaxf(fmaxf(a, b), c);   // clang fuses to v_max3_f32
}

__device__ __forceinline__ void gload_lds16(const void* g, void* l) {
  __builtin_amdgcn_global_load_lds(
      (const __attribute__((address_space(1))) void*)g,
      (__attribute__((address_space(3))) void*)l, 16, 0, 0);
}

// ---------------------------------------------------------------------------
// f32 -> bf16 cast (unchanged).
// ---------------------------------------------------------------------------
__global__ __launch_bounds__(256, 4) void cvt_kernel(
    const float* __restrict__ x,  const float* __restrict__ qw,
    const float* __restrict__ kw, const float* __restrict__ vw,
    const float* __restrict__ ow, unsigned short* __restrict__ dst)
{
  const int seg = blockIdx.y;
  const float* src;
  size_t doff;
  if (seg < 4)       { src = x + (size_t)seg * 1048576; doff = (size_t)seg * 1048576; }
  else if (seg == 4) { src = qw; doff = 4194304u; }
  else if (seg == 5) { src = kw; doff = 4194304u + 1048576u; }
  else if (seg == 6) { src = vw; doff = 4194304u + 2097152u; }
  else               { src = ow; doff = 4194304u + 3145728u; }
  const size_t i = ((size_t)blockIdx.x * 256 + threadIdx.x) * 4;
  float4v v = *(const float4v*)(src + i);
  short4v p;
#pragma unroll
  for (int r = 0; r < 4; ++r) p[r] = (short)f2bf(v[r]);
  *(short4v*)(dst + doff + i) = p;
}

// ---------------------------------------------------------------------------
// GEMM: out = X @ W^T + bias.  REVERTED to the round-9 configuration (the
// session's best measured state, 167.0us): BK=64 two-barrier K-loop, T2 XOR
// swizzle (rows 128B, chunk^(row&7), inverse-swizzled global source), T1
// XCD swizzle, 3 blocks/CU.  Round-10's BK=32 dbuf single-barrier variant
// regressed +3.9us (half the MFMA per staged batch, 2x loop overhead; same
// barrier count) -- the BK=64 2-barrier shape is this structure's optimum.
// ---------------------------------------------------------------------------
template <int TN>
__global__ __launch_bounds__(256, 3) void gemm_kernel(
    const unsigned short* __restrict__ X,
    const unsigned short* __restrict__ W0, const unsigned short* __restrict__ W1,
    const unsigned short* __restrict__ W2,
    const float* __restrict__ Bi0, const float* __restrict__ Bi1,
    const float* __restrict__ Bi2,
    unsigned short* O0, unsigned short* O1, unsigned short* O2,
    float* OutF, int md0, int md1, int md2)
{
  constexpr int NJ = TN / 32;     // 16-col acc tiles per wave
  constexpr int SMEM = (TN == 128) ? 32768 : 24576;  // As 16KB + Bs TN*128
  constexpr int GX = (TN == 128) ? 8 : 16;   // gridDim.x (compile-time)
  constexpr int CPX = (GX * 32) / 8;         // blocks per XCD chunk
  const int z = blockIdx.z;
  const unsigned short* W  = (z == 0) ? W0  : ((z == 1) ? W1  : W2);
  const float* Bi          = (z == 0) ? Bi0 : ((z == 1) ? Bi1 : Bi2);
  unsigned short* Out      = (z == 0) ? O0  : ((z == 1) ? O1  : O2);
  const int mode           = (z == 0) ? md0 : ((z == 1) ? md1 : md2);

  __shared__ __align__(16) char smem[SMEM];
  char* As = smem;
  char* Bs = smem + 16384;
  float* tb = (float*)smem;      // mode-1 transpose buffer (aliases staging)

  const int t = threadIdx.x, l = t & 63;
  const int w = t >> 6, lr = l & 15, lg = l >> 4;

  // XCD swizzle: dispatch slot bid -> logical tile sw (bijective, nwg%8==0)
  const int bid = (int)blockIdx.y * GX + (int)blockIdx.x;
  const int sw  = (bid & 7) * CPX + (bid >> 3);
  const int n0 = (sw % GX) * TN, m0 = (sw / GX) * 128;
  const int wm = (w >> 1) * 64, wn = (w & 1) * (TN / 2);

  float4v acc[4][NJ];
#pragma unroll
  for (int i = 0; i < 4; ++i)
#pragma unroll
    for (int j = 0; j < NJ; ++j) acc[i][j] = (float4v){0.f, 0.f, 0.f, 0.f};

  // staging decomposition: idx = t + 256*cc covers (row = idx>>3, chunk =
  // idx&7); 16B per (row,chunk); source chunk pre-swizzled: sch = ch^(row&7)
  for (int k0 = 0; k0 < 1024; k0 += 64) {
    __syncthreads();
#pragma unroll
    for (int cc = 0; cc < 4; ++cc) {
      const int idx = t + 256 * cc;
      const int r = idx >> 3, ch = idx & 7;
      const int sch = ch ^ (r & 7);
      gload_lds16(X + (size_t)(m0 + r) * 1024 + k0 + sch * 8, As + idx * 16);
    }
#pragma unroll
    for (int cc = 0; cc < NJ; ++cc) {
      const int idx = t + 256 * cc;
      const int r = idx >> 3, ch = idx & 7;
      const int sch = ch ^ (r & 7);
      gload_lds16(W + (size_t)(n0 + r) * 1024 + k0 + sch * 8, Bs + idx * 16);
    }
    __syncthreads();

#pragma unroll
    for (int kk = 0; kk < 2; ++kk) {
      short8 af[4], bfr[NJ];
#pragma unroll
      for (int i = 0; i < 4; ++i) {
        const int row = wm + i * 16 + lr;
        af[i] = *(const short8*)(As + row * 128 + (((kk * 4 + lg) ^ (row & 7)) << 4));
      }
#pragma unroll
      for (int j = 0; j < NJ; ++j) {
        const int row = wn + j * 16 + lr;
        bfr[j] = *(const short8*)(Bs + row * 128 + (((kk * 4 + lg) ^ (row & 7)) << 4));
      }
#pragma unroll
      for (int i = 0; i < 4; ++i)
#pragma unroll
        for (int j = 0; j < NJ; ++j)
          acc[i][j] = __builtin_amdgcn_mfma_f32_16x16x32_bf16(af[i], bfr[j], acc[i][j], 0, 0, 0);
    }
  }

  float bv[NJ];
#pragma unroll
  for (int j = 0; j < NJ; ++j) bv[j] = Bi[n0 + wn + j * 16 + lr];

  if constexpr (TN == 128) {
    if (mode == 1) {
      __syncthreads();   // staging LDS now dead; safe to overwrite as tb
      const int rbase = (w >> 1) * 16;
      const int row16 = t >> 3, chunk = t & 7;
#pragma unroll
      for (int i = 0; i < 4; ++i) {
#pragma unroll
        for (int j = 0; j < 4; ++j)
#pragma unroll
          for (int r = 0; r < 4; ++r)
            tb[(rbase + lg * 4 + r) * 132 + wn + j * 16 + lr] = acc[i][j][r] + bv[j];
        __syncthreads();
        const int grow = m0 + ((row16 < 16) ? (i * 16 + row16) : (64 + i * 16 + row16 - 16));
        const int b = grow >> 11, sl = grow & 2047;
        const int colg = n0 + chunk * 16;
        const int hh = colg >> 6, d0 = colg & 63;
        float4v v4[4];
#pragma unroll
        for (int q = 0; q < 4; ++q)
          v4[q] = *(const float4v*)(tb + row16 * 132 + chunk * 16 + q * 4);
        uint4v lo, hi;
#pragma unroll
        for (int q = 0; q < 2; ++q) {
          lo[q * 2]     = pkbf(v4[q][0], v4[q][1]);
          lo[q * 2 + 1] = pkbf(v4[q][2], v4[q][3]);
          hi[q * 2]     = pkbf(v4[q + 2][0], v4[q + 2][1]);
          hi[q * 2 + 1] = pkbf(v4[q + 2][2], v4[q + 2][3]);
        }
        unsigned short* dst = Out + ((size_t)(b * H_ + hh) * S_ + sl) * HD_ + d0;
        *(short8*)dst = __builtin_bit_cast(short8, lo);
        *(short8*)(dst + 8) = __builtin_bit_cast(short8, hi);
        __syncthreads();
      }
      return;
    }
    if (mode == 2) {
#pragma unroll
      for (int i = 0; i < 4; ++i) {
        const int rowb = m0 + wm + i * 16 + lg * 4;
#pragma unroll
        for (int j = 0; j < 4; ++j) {
          const int col = n0 + wn + j * 16 + lr;
          const int b = rowb >> 11, s = rowb & 2047;
          const int hh = col >> 6, d = col & 63;
          // k-group interleave within each 32-elem s-block (see header)
          const int gI = (s >> 2) & 7;
          const int gP = ((gI & 3) << 1) | (gI >> 2);
          const int sN = (s & ~31) | (gP << 2);
          uint2v pk2;
          pk2[0] = pkbf(acc[i][j][0] + bv[j], acc[i][j][1] + bv[j]);
          pk2[1] = pkbf(acc[i][j][2] + bv[j], acc[i][j][3] + bv[j]);
          *(short4v*)(Out + ((size_t)(b * H_ + hh) * HD_ + d) * S_ + sN) =
              __builtin_bit_cast(short4v, pk2);
        }
      }
      return;
    }
  }
  // mode 0: f32 out
#pragma unroll
  for (int i = 0; i < 4; ++i) {
    const int rowb = m0 + wm + i * 16 + lg * 4;
#pragma unroll
    for (int j = 0; j < NJ; ++j) {
      const int col = n0 + wn + j * 16 + lr;
#pragma unroll
      for (int r = 0; r < 4; ++r)
        OutF[(size_t)(rowb + r) * 1024 + col] = acc[i][j][r] + bv[j];
    }
  }
}

// ---------------------------------------------------------------------------
// Flash attention v12 (unchanged -- round-9 winner): v9 structure with
// REVERSED tile order (j from the diagonal down to 0).  ALiBi max-score
// decreases per tile, so the defer-max rescale stops firing after tile 1.
// ---------------------------------------------------------------------------
__global__ __launch_bounds__(256, 4) void attn_kernel(
    const unsigned short* __restrict__ Q, const unsigned short* __restrict__ K,
    const unsigned short* __restrict__ VT, unsigned short* __restrict__ O)
{
  // K dbuf 2x8KB + V dbuf 2x8KB; epilogue transpose buffer aliases [0,17664)
  __shared__ __align__(16) char smem[32768];

  const int t = threadIdx.x, l = t & 63;
  const int w = t >> 6, lr = l & 15, lg = l >> 4;
  const int bh = blockIdx.x;
  const int it = 31 - (int)blockIdx.y;   // LPT: heavy tiles first
  const int h = bh & 15;

  const unsigned short* qbp = Q + (size_t)bh * S_ * HD_;
  const unsigned short* kbp = K + (size_t)bh * S_ * HD_;
  const unsigned short* vbp = VT + (size_t)bh * HD_ * S_;

  const float slope2 = __builtin_amdgcn_exp2f(-0.5f * (float)(h + 1)) * LOG2E;
  const float qksc = 0.125f * LOG2E;

  const int g0 = t, g1 = t + 256;
  const int sr0 = g0 >> 3, sc0 = (g0 & 7) ^ (sr0 & 7);
  const int sr1 = g1 >> 3, sc1 = (g1 & 7) ^ (sr1 & 7);

  const int fchunk = ((4 + lg) ^ (lr & 7)) * 16;   // ks=1
  const int fchunk0 = ((lg) ^ (lr & 7)) * 16;      // ks=0

  const int qrow = it * 64 + w * 16;
  const int qpos = qrow + lr;

  short8 ones;
#pragma unroll
  for (int e = 0; e < 8; ++e) ones[e] = (short)0x3F80;  // bf16 1.0

  short8 qf[2];
#pragma unroll
  for (int ks = 0; ks < 2; ++ks)
    qf[ks] = *(const short8*)(qbp + (size_t)(qrow + lr) * HD_ + ks * 32 + lg * 8);

  // hoisted ALiBi bias constants: kb[nj*4+r] = slope2*(nj*16+lg*4+r)
  float kb[16];
#pragma unroll
  for (int nj = 0; nj < 4; ++nj)
#pragma unroll
    for (int r = 0; r < 4; ++r)
      kb[nj * 4 + r] = slope2 * (float)(nj * 16 + lg * 4 + r);
  const float jbstep = slope2 * 64.0f;
  float jb = jbstep * (float)it;            // slope2 * 64 * j, descending

  const float4v z4 = (float4v){0.f, 0.f, 0.f, 0.f};

  float4v o_acc[4], l_acc;
#pragma unroll
  for (int dt = 0; dt < 4; ++dt) o_acc[dt] = z4;
  l_acc = z4;
  float m_st = -1e30f;

  // prefetch tile j=it into buffer (it&1)
  {
    char* K0 = smem + ((it & 1) ? 8192 : 0);
    char* V0 = smem + 16384 + ((it & 1) ? 8192 : 0);
    gload_lds16(kbp + (size_t)(it * 64 + sr0) * HD_ + sc0 * 8, K0 + g0 * 16);
    gload_lds16(kbp + (size_t)(it * 64 + sr1) * HD_ + sc1 * 8, K0 + g1 * 16);
    gload_lds16(vbp + (size_t)sr0 * S_ + it * 64 + sc0 * 8, V0 + g0 * 16);
    gload_lds16(vbp + (size_t)sr1 * S_ + it * 64 + sc1 * 8, V0 + g1 * 16);
  }
  __syncthreads();

  const int vcl = lr & 7;

  for (int j = it; j >= 0; --j) {
    const int cur = j & 1;
    char* Ks = smem + (cur ? 8192 : 0);
    char* Vs = smem + 16384 + (cur ? 8192 : 0);
    if (j > 0) {
      char* Kn = smem + (cur ? 0 : 8192);
      char* Vn = smem + 16384 + (cur ? 0 : 8192);
      const int jn = j - 1;
      gload_lds16(kbp + (size_t)(jn * 64 + sr0) * HD_ + sc0 * 8, Kn + g0 * 16);
      gload_lds16(kbp + (size_t)(jn * 64 + sr1) * HD_ + sc1 * 8, Kn + g1 * 16);
      gload_lds16(vbp + (size_t)sr0 * S_ + jn * 64 + sc0 * 8, Vn + g0 * 16);
      gload_lds16(vbp + (size_t)sr1 * S_ + jn * 64 + sc1 * 8, Vn + g1 * 16);
    }

    // S^T = K Q^T
    float4v s_acc[4];
    __builtin_amdgcn_s_setprio(1);
#pragma unroll
    for (int nj = 0; nj < 4; ++nj) {
      short8 kf0 = *(const short8*)(Ks + (nj * 16 + lr) * 128 + fchunk0);
      float4v t0 = __builtin_amdgcn_mfma_f32_16x16x32_bf16(kf0, qf[0], z4, 0, 0, 0);
      short8 kf1 = *(const short8*)(Ks + (nj * 16 + lr) * 128 + fchunk);
      s_acc[nj] = __builtin_amdgcn_mfma_f32_16x16x32_bf16(kf1, qf[1], t0, 0, 0, 0);
    }
    __builtin_amdgcn_s_setprio(0);

    // scale + ALiBi (jb-relative domain: t = s*qksc + kb_e; absolute = t + jb)
#pragma unroll
    for (int nj = 0; nj < 4; ++nj)
#pragma unroll
      for (int r = 0; r < 4; ++r)
        s_acc[nj][r] = s_acc[nj][r] * qksc + kb[nj * 4 + r];
    if (j == it) {
#pragma unroll
      for (int nj = 0; nj < 4; ++nj)
#pragma unroll
        for (int r = 0; r < 4; ++r) {
          const int kpos = j * 64 + nj * 16 + lg * 4 + r;
          if (kpos > qpos) s_acc[nj][r] = -1e30f;
        }
    }

    // online softmax: max3 tree + 2 cross-quad shuffles; defer-max THR=8
    float a0 = max3f(s_acc[0][0], s_acc[0][1], s_acc[0][2]);
    float a1 = max3f(s_acc[0][3], s_acc[1][0], s_acc[1][1]);
    float a2 = max3f(s_acc[1][2], s_acc[1][3], s_acc[2][0]);
    float a3 = max3f(s_acc[2][1], s_acc[2][2], s_acc[2][3]);
    float a4 = max3f(s_acc[3][0], s_acc[3][1], s_acc[3][2]);
    float b0 = max3f(a0, a1, a2);
    float b1 = max3f(a3, a4, s_acc[3][3]);
    float mxt = fmaxf(b0, b1);
    mxt = fmaxf(mxt, __shfl_xor(mxt, 16, 64));
    mxt = fmaxf(mxt, __shfl_xor(mxt, 32, 64));
    const float mx = mxt + jb;               // absolute-domain tile max
    if (__any(mx > m_st + 8.0f)) {
      const float mn = fmaxf(m_st, mx);
      const float alpha = __builtin_amdgcn_exp2f(m_st - mn);
      m_st = mn;
#pragma unroll
      for (int dt = 0; dt < 4; ++dt)
#pragma unroll
        for (int r = 0; r < 4; ++r) o_acc[dt][r] *= alpha;
#pragma unroll
      for (int r = 0; r < 4; ++r) l_acc[r] *= alpha;
    }
    const float c1 = m_st - jb;              // exp2 arg = t - c1 = abs - m_st
#pragma unroll
    for (int nj = 0; nj < 4; ++nj)
#pragma unroll
      for (int r = 0; r < 4; ++r)
        s_acc[nj][r] = __builtin_amdgcn_exp2f(s_acc[nj][r] - c1);

    // P^T -> bf16 K=32 B-fragments via packed cvt
    short8 pT[2];
#pragma unroll
    for (int njp = 0; njp < 2; ++njp) {
      uint4v u;
      u[0] = pkbf(s_acc[njp * 2][0], s_acc[njp * 2][1]);
      u[1] = pkbf(s_acc[njp * 2][2], s_acc[njp * 2][3]);
      u[2] = pkbf(s_acc[njp * 2 + 1][0], s_acc[njp * 2 + 1][1]);
      u[3] = pkbf(s_acc[njp * 2 + 1][2], s_acc[njp * 2 + 1][3]);
      pT[njp] = __builtin_bit_cast(short8, u);
    }

    __builtin_amdgcn_s_setprio(1);
    // l += rowsum(P) via ones-A MFMA (off the critical path, runs with PV)
    l_acc = __builtin_amdgcn_mfma_f32_16x16x32_bf16(ones, pT[0], l_acc, 0, 0, 0);
    l_acc = __builtin_amdgcn_mfma_f32_16x16x32_bf16(ones, pT[1], l_acc, 0, 0, 0);

    // O^T += V^T P^T  (interleaved VT: one b128 per fragment, conflict-free)
#pragma unroll
    for (int dt = 0; dt < 4; ++dt) {
      const char* rowp = Vs + (dt * 16 + lr) * 128;
#pragma unroll
      for (int njp = 0; njp < 2; ++njp) {
        short8 vf8 = *(const short8*)(rowp + (((njp * 4 + lg) ^ vcl) << 4));
        o_acc[dt] = __builtin_amdgcn_mfma_f32_16x16x32_bf16(vf8, pT[njp], o_acc[dt], 0, 0, 0);
      }
    }
    __builtin_amdgcn_s_setprio(0);
    jb -= jbstep;
    __syncthreads();
  }

  // epilogue: un-transpose O^T via wave-private LDS (aliases dead K dbuf)
  char* tw = smem + w * 4416;
#pragma unroll
  for (int dt = 0; dt < 4; ++dt)
#pragma unroll
    for (int r = 0; r < 4; ++r)
      *(float*)(tw + ((dt * 16 + lg * 4 + r) * 17 + lr) * 4) = o_acc[dt][r];
  if (lg == 0) *(float*)(tw + 4352 + lr * 4) = l_acc[0];

  const int q2 = l >> 2, dbase = (l & 3) * 16;
  const float invl = 1.0f / *(const float*)(tw + 4352 + q2 * 4);
  uint4v os0, os1;
#pragma unroll
  for (int k = 0; k < 8; ++k) {
    const float va = *(const float*)(tw + ((dbase + 2 * k) * 17 + q2) * 4) * invl;
    const float vb = *(const float*)(tw + ((dbase + 2 * k + 1) * 17 + q2) * 4) * invl;
    if (k < 4) os0[k] = pkbf(va, vb); else os1[k - 4] = pkbf(va, vb);
  }
  const int brow = (bh >> 4) * S_;
  unsigned short* op = O + (size_t)(brow + qrow + q2) * 1024 + h * 64 + dbase;
  *(short8*)op = __builtin_bit_cast(short8, os0);
  *(short8*)(op + 8) = __builtin_bit_cast(short8, os1);
}

extern "C" void kernel_launch(void* const* d_in, const int* in_sizes, int n_in,
                              void* d_out, int out_size, void* d_ws, size_t ws_size,
                              hipStream_t stream) {
  (void)in_sizes; (void)n_in; (void)out_size; (void)ws_size;
  const float* x  = (const float*)d_in[0];
  const float* qw = (const float*)d_in[1];
  const float* qb = (const float*)d_in[2];
  const float* kw = (const float*)d_in[3];
  const float* kb = (const float*)d_in[4];
  const float* vw = (const float*)d_in[5];
  const float* vb = (const float*)d_in[6];
  const float* ow = (const float*)d_in[7];
  const float* ob = (const float*)d_in[8];
  float* out = (float*)d_out;

  unsigned short* xb  = (unsigned short*)d_ws;              // [4096,1024] bf16
  unsigned short* qwb = xb  + (size_t)M_ * D_;
  unsigned short* kwb = qwb + (size_t)D_ * D_;
  unsigned short* vwb = kwb + (size_t)D_ * D_;
  unsigned short* owb = vwb + (size_t)D_ * D_;
  unsigned short* qws = owb + (size_t)D_ * D_;              // [B,H,S,hd]
  unsigned short* kws = qws + (size_t)M_ * D_;              // [B,H,S,hd]
  unsigned short* vws = kws + (size_t)M_ * D_;              // [B,H,hd,S] interleaved
  unsigned short* aws = vws + (size_t)M_ * D_;              // [B*S, H*hd]

  cvt_kernel<<<dim3(1024, 8), dim3(256), 0, stream>>>(x, qw, kw, vw, ow, xb);
  gemm_kernel<128><<<dim3(8, 32, 3), dim3(256), 0, stream>>>(
      xb, qwb, kwb, vwb, qb, kb, vb, qws, kws, vws, out, 1, 1, 2);
  attn_kernel<<<dim3(32, 32), dim3(256), 0, stream>>>(qws, kws, vws, aws);
  gemm_kernel<64><<<dim3(16, 32, 1), dim3(256), 0, stream>>>(
      aws, owb, owb, owb, ob, ob, ob, aws, aws, aws, out, 0, 0, 0);
}